// Round 2
// baseline (1302.747 us; speedup 1.0000x reference)
//
#include <hip/hip_runtime.h>

// FlashAttention fwd, causal, no scale. B=2,H=16,S=2048,D=128, fp32 in/out.
// Strategy: pre-convert Q,K -> fp16 and V -> fp16 transposed [bh][d][s] in d_ws,
// then flash-attention main kernel: BM=128 rows/WG, BN=64 key tile,
// mfma_f32_16x16x32_f16, global_load_lds(16B) staging with XOR swizzle so all
// frag ds_read_b128 are conflict-free. Needs ws_size >= 48 MiB.
// fp16 (not bf16) internally: no-scale attention has S ~ N(0,128); bf16's
// 2^-8 rounding on Q,K gave absmax 0.155 > 0.104 threshold (R1). fp16's
// 2^-11 cuts that 8x at identical MFMA rate.

#define SQ 2048
#define DH 128
#define BM 128
#define BN 64
#define NELEM 8388608   // B*H*S*D

typedef _Float16 f16x8 __attribute__((ext_vector_type(8)));
typedef float f32x4 __attribute__((ext_vector_type(4)));
typedef unsigned short u16x8 __attribute__((ext_vector_type(8)));

typedef __attribute__((address_space(3))) void lds_t;
typedef __attribute__((address_space(1))) void gmem_t;

__device__ __forceinline__ void gload16(void* lds, const void* g) {
  __builtin_amdgcn_global_load_lds((const gmem_t*)g, (lds_t*)lds, 16, 0, 0);
}

__device__ __forceinline__ unsigned short f2h(float f) {
  return __builtin_bit_cast(unsigned short, (_Float16)f);   // v_cvt_f16_f32, RNE
}

__device__ __forceinline__ float redmax16(float x) {
  x = fmaxf(x, __shfl_xor(x, 1));
  x = fmaxf(x, __shfl_xor(x, 2));
  x = fmaxf(x, __shfl_xor(x, 4));
  x = fmaxf(x, __shfl_xor(x, 8));
  return x;
}
__device__ __forceinline__ float redsum16(float x) {
  x += __shfl_xor(x, 1);
  x += __shfl_xor(x, 2);
  x += __shfl_xor(x, 4);
  x += __shfl_xor(x, 8);
  return x;
}

// ---------------- pre-kernel 1: Q,K fp32 -> fp16 (flat) ----------------
__global__ __launch_bounds__(256) void convqk(const float* __restrict__ q,
                                              const float* __restrict__ k,
                                              unsigned short* __restrict__ qo,
                                              unsigned short* __restrict__ ko) {
  const int NT = NELEM / 4;  // float4 chunks per tensor
  for (int i = blockIdx.x * 256 + threadIdx.x; i < 2 * NT; i += gridDim.x * 256) {
    const float4* src; unsigned short* dst; int j = i;
    if (i < NT) { src = (const float4*)q; dst = qo; }
    else        { src = (const float4*)k; dst = ko; j -= NT; }
    float4 v = src[j];
    ushort4 o;
    o.x = f2h(v.x); o.y = f2h(v.y); o.z = f2h(v.z); o.w = f2h(v.w);
    *(ushort4*)(dst + (size_t)j * 4) = o;
  }
}

// ---------------- pre-kernel 2: V [bh][s][d] fp32 -> Vt [bh][d][s] fp16 ----
__global__ __launch_bounds__(256) void transv(const float* __restrict__ v,
                                              unsigned short* __restrict__ vt) {
  __shared__ unsigned short lv[64 * 128];  // [s_local][d], 16KB
  const int tid = threadIdx.x;
  const int bh = blockIdx.y;
  const int s0 = blockIdx.x * 64;
  const float* vsrc = v + ((size_t)bh * SQ + s0) * DH;
  // stage + convert (coalesced float4 reads)
  for (int it = 0; it < 8; ++it) {
    int fi = it * 256 + tid;        // float4 index, 32 per row
    int sL = fi >> 5;
    int dL = (fi & 31) * 4;
    float4 val = *(const float4*)(vsrc + (size_t)sL * DH + dL);
    lv[sL * 128 + dL + 0] = f2h(val.x);
    lv[sL * 128 + dL + 1] = f2h(val.y);
    lv[sL * 128 + dL + 2] = f2h(val.z);
    lv[sL * 128 + dL + 3] = f2h(val.w);
  }
  __syncthreads();
  // transposed write-out: each thread emits 8 keys of one d-row (16B)
  for (int it = 0; it < 4; ++it) {
    int ci = it * 256 + tid;        // 1024 chunks: d = ci&127, sgroup = ci>>7
    int dL = ci & 127;
    int sg = ci >> 7;
    u16x8 o;
    #pragma unroll
    for (int j = 0; j < 8; ++j) o[j] = lv[(sg * 8 + j) * 128 + dL];
    *(u16x8*)(vt + ((size_t)bh * DH + dL) * SQ + s0 + sg * 8) = o;
  }
}

// ---------------- main flash-attention kernel ----------------
__global__ __launch_bounds__(256) void fattn(const unsigned short* __restrict__ Qb,
                                             const unsigned short* __restrict__ Kb,
                                             const unsigned short* __restrict__ Vt,
                                             float* __restrict__ Out) {
  __shared__ char smem[49152];   // [0,16K) K-tile, [16K,32K) Vt-tile, [32K,48K) P (4K/wave)
                                 // Q staging aliases [0,32K)
  const int tid  = threadIdx.x;
  const int wave = tid >> 6;
  const int lane = tid & 63;
  const int quad = lane >> 4;
  const int c    = lane & 15;
  const int bh   = blockIdx.y;
  const int qb   = 15 - (int)blockIdx.x;           // big blocks dispatched first
  const int mt0i = wave, mt1i = 7 - wave;          // causal-balanced m-tile pair
  const int rowg0 = qb * BM + mt0i * 16;
  const int rowg1 = qb * BM + mt1i * 16;

  char* sK = smem;
  char* sV = smem + 16384;
  char* sP = smem + 32768 + wave * 4096;

  // ---- stage Q tile (128 rows x 128 d, fp16, swizzled), read frags ----
  const unsigned short* Qbase = Qb + ((size_t)bh * SQ + qb * BM) * DH;
  #pragma unroll
  for (int it = 0; it < 8; ++it) {
    int gi  = it * 256 + tid;          // group index 0..2047 (16 groups/row)
    int row = gi >> 4;
    int dg  = (gi & 15) ^ (row & 7);   // swizzle: LDS group holds this d-group
    gload16(smem + (it * 256 + wave * 64) * 16, Qbase + (size_t)row * DH + dg * 8);
  }
  __syncthreads();
  f16x8 qf[2][4];
  #pragma unroll
  for (int mt = 0; mt < 2; ++mt) {
    int lr = (mt ? mt1i : mt0i) * 16 + c;
    #pragma unroll
    for (int ch = 0; ch < 4; ++ch) {
      int sg = (ch * 4 + quad) ^ (lr & 7);
      qf[mt][ch] = *(const f16x8*)(smem + lr * 256 + sg * 16);
    }
  }
  __syncthreads();

  f32x4 acc[2][8];
  #pragma unroll
  for (int mt = 0; mt < 2; ++mt)
    #pragma unroll
    for (int dt = 0; dt < 8; ++dt) acc[mt][dt] = (f32x4){0.f, 0.f, 0.f, 0.f};
  float mrow[2][4], lrow[2][4];
  #pragma unroll
  for (int mt = 0; mt < 2; ++mt)
    #pragma unroll
    for (int r = 0; r < 4; ++r) { mrow[mt][r] = -1e30f; lrow[mt][r] = 0.f; }

  const unsigned short* Kbase = Kb + (size_t)bh * SQ * DH;
  const unsigned short* Vbase = Vt + (size_t)bh * DH * SQ;
  const int nkt = 2 * qb + 2;

  for (int kt = 0; kt < nkt; ++kt) {
    const int k0 = kt * BN;
    // ---- stage K tile (64 keys x 128 d) and Vt tile (128 d x 64 keys) ----
    #pragma unroll
    for (int it = 0; it < 4; ++it) {
      int gi  = it * 256 + tid;
      int key = gi >> 4;
      int dg  = (gi & 15) ^ (key & 7);
      gload16(sK + (it * 256 + wave * 64) * 16,
              Kbase + (size_t)(k0 + key) * DH + dg * 8);
    }
    #pragma unroll
    for (int it = 0; it < 4; ++it) {
      int gi = it * 256 + tid;
      int d  = gi >> 3;
      int kg = (gi & 7) ^ (d & 7);
      gload16(sV + (it * 256 + wave * 64) * 16,
              Vbase + (size_t)d * SQ + k0 + kg * 8);
    }
    __syncthreads();

    const bool act0 = (k0 <= rowg0 + 15);   // act for mt1 is always true
    const int mstart = act0 ? 0 : 1;

    // ---- S = Q K^T (16x16x32 mfma), C-layout: col=lane&15, row=quad*4+r ----
    f32x4 sc[2][4];
    #pragma unroll
    for (int mt = 0; mt < 2; ++mt)
      #pragma unroll
      for (int nt = 0; nt < 4; ++nt) sc[mt][nt] = (f32x4){0.f, 0.f, 0.f, 0.f};
    #pragma unroll
    for (int nt = 0; nt < 4; ++nt) {
      int keyl = nt * 16 + c;
      #pragma unroll
      for (int ch = 0; ch < 4; ++ch) {
        int sg = (ch * 4 + quad) ^ (keyl & 7);
        f16x8 kf = *(const f16x8*)(sK + keyl * 256 + sg * 16);
        sc[0][nt] = __builtin_amdgcn_mfma_f32_16x16x32_f16(qf[0][ch], kf, sc[0][nt], 0, 0, 0);
        sc[1][nt] = __builtin_amdgcn_mfma_f32_16x16x32_f16(qf[1][ch], kf, sc[1][nt], 0, 0, 0);
      }
    }

    // ---- online softmax + P write (fp16, swizzled per-wave region) ----
    for (int mt = mstart; mt < 2; ++mt) {
      const int rowgm = mt ? rowg1 : rowg0;
      if (k0 + 63 > rowgm) {   // causal mask needed on this tile
        #pragma unroll
        for (int nt = 0; nt < 4; ++nt) {
          int key = k0 + nt * 16 + c;
          #pragma unroll
          for (int r = 0; r < 4; ++r) {
            int row = rowgm + quad * 4 + r;
            if (key > row) sc[mt][nt][r] = -1e30f;
          }
        }
      }
      #pragma unroll
      for (int r = 0; r < 4; ++r) {
        float cm = fmaxf(fmaxf(sc[mt][0][r], sc[mt][1][r]),
                         fmaxf(sc[mt][2][r], sc[mt][3][r]));
        cm = redmax16(cm);
        float mo = mrow[mt][r];
        float mn = fmaxf(mo, cm);
        float al = __expf(mo - mn);
        float rs = 0.f;
        int lrp = mt * 16 + quad * 4 + r;
        #pragma unroll
        for (int nt = 0; nt < 4; ++nt) {
          float p = __expf(sc[mt][nt][r] - mn);
          rs += p;
          int colg = nt * 16 + c;
          int sg = (colg >> 3) ^ (lrp & 7);
          *(unsigned short*)(sP + lrp * 128 + sg * 16 + (colg & 7) * 2) = f2h(p);
        }
        rs = redsum16(rs);
        lrow[mt][r] = lrow[mt][r] * al + rs;
        mrow[mt][r] = mn;
        #pragma unroll
        for (int dt = 0; dt < 8; ++dt) acc[mt][dt][r] *= al;
      }
    }

    // ---- O += P V  (P: A-layout from LDS, Vt: B-layout) ----
    #pragma unroll
    for (int ch = 0; ch < 2; ++ch) {
      f16x8 pf0, pf1;
      if (act0) {
        int lrp = c;                      // mt0 rows 0..15 of wave region
        int sg = (ch * 4 + quad) ^ (lrp & 7);
        pf0 = *(const f16x8*)(sP + lrp * 128 + sg * 16);
      }
      {
        int lrp = 16 + c;
        int sg = (ch * 4 + quad) ^ (lrp & 7);
        pf1 = *(const f16x8*)(sP + lrp * 128 + sg * 16);
      }
      #pragma unroll
      for (int dt = 0; dt < 8; ++dt) {
        int d = dt * 16 + c;
        int sg = (ch * 4 + quad) ^ (d & 7);
        f16x8 vf = *(const f16x8*)(sV + d * 128 + sg * 16);
        if (act0)
          acc[0][dt] = __builtin_amdgcn_mfma_f32_16x16x32_f16(pf0, vf, acc[0][dt], 0, 0, 0);
        acc[1][dt] = __builtin_amdgcn_mfma_f32_16x16x32_f16(pf1, vf, acc[1][dt], 0, 0, 0);
      }
    }
    __syncthreads();   // protect sK/sV/sP before next stage
  }

  // ---- epilogue: O / l ----
  #pragma unroll
  for (int mt = 0; mt < 2; ++mt) {
    const int rowgm = mt ? rowg1 : rowg0;
    #pragma unroll
    for (int r = 0; r < 4; ++r) {
      float inv = 1.0f / lrow[mt][r];
      int row = rowgm + quad * 4 + r;
      float* op = Out + ((size_t)bh * SQ + row) * DH + c;
      #pragma unroll
      for (int dt = 0; dt < 8; ++dt) op[dt * 16] = acc[mt][dt][r] * inv;
    }
  }
}

extern "C" void kernel_launch(void* const* d_in, const int* in_sizes, int n_in,
                              void* d_out, int out_size, void* d_ws, size_t ws_size,
                              hipStream_t stream) {
  const float* q = (const float*)d_in[0];
  const float* k = (const float*)d_in[1];
  const float* v = (const float*)d_in[2];
  // d_in[3] (mask) is guaranteed tril-causal; handled analytically.
  float* out = (float*)d_out;

  unsigned short* qws = (unsigned short*)d_ws;           // 16 MiB
  unsigned short* kws = qws + NELEM;                     // 16 MiB
  unsigned short* vws = kws + NELEM;                     // 16 MiB (transposed)

  convqk<<<4096, 256, 0, stream>>>(q, k, qws, kws);
  transv<<<dim3(SQ / 64, 32), 256, 0, stream>>>(v, vws);
  fattn<<<dim3(16, 32), 256, 0, stream>>>(qws, kws, vws, out);
}

// Round 3
// 381.159 us; speedup vs baseline: 3.4179x; 3.4179x over previous
//
#include <hip/hip_runtime.h>

// FlashAttention fwd, causal, no scale. B=2,H=16,S=2048,D=128, fp32 in/out.
// Strategy: pre-convert Q,K -> fp16 and V -> fp16 transposed [bh][d][s] in d_ws,
// then flash-attention main kernel: BM=128 rows/WG, BN=64 key tile,
// mfma_f32_16x16x32_f16, global_load_lds(16B) staging with XOR swizzle so all
// frag ds_read_b128 are conflict-free. Needs ws_size >= 48 MiB.
// fp16 (not bf16) internally: no-scale attention has S ~ N(0,128); bf16 gave
// absmax 0.155 > 0.104 (R1); fp16 gives 0.031 (R2).
// R2->R3: softmax mt-loop had RUNTIME lower bound (mstart) -> no unroll ->
// dynamic indexing of sc/acc/mrow/lrow -> scratch demotion -> 1.78 GB of
// scratch write traffic per dispatch (53x output size), MfmaUtil 1.2%.
// Fixed: compile-time unrolled mt loop with wave-uniform guard inside.

#define SQ 2048
#define DH 128
#define BM 128
#define BN 64
#define NELEM 8388608   // B*H*S*D

typedef _Float16 f16x8 __attribute__((ext_vector_type(8)));
typedef float f32x4 __attribute__((ext_vector_type(4)));
typedef unsigned short u16x8 __attribute__((ext_vector_type(8)));

typedef __attribute__((address_space(3))) void lds_t;
typedef __attribute__((address_space(1))) void gmem_t;

__device__ __forceinline__ void gload16(void* lds, const void* g) {
  __builtin_amdgcn_global_load_lds((const gmem_t*)g, (lds_t*)lds, 16, 0, 0);
}

__device__ __forceinline__ unsigned short f2h(float f) {
  return __builtin_bit_cast(unsigned short, (_Float16)f);   // v_cvt_f16_f32, RNE
}

__device__ __forceinline__ float redmax16(float x) {
  x = fmaxf(x, __shfl_xor(x, 1));
  x = fmaxf(x, __shfl_xor(x, 2));
  x = fmaxf(x, __shfl_xor(x, 4));
  x = fmaxf(x, __shfl_xor(x, 8));
  return x;
}
__device__ __forceinline__ float redsum16(float x) {
  x += __shfl_xor(x, 1);
  x += __shfl_xor(x, 2);
  x += __shfl_xor(x, 4);
  x += __shfl_xor(x, 8);
  return x;
}

// ---------------- pre-kernel 1: Q,K fp32 -> fp16 (flat) ----------------
__global__ __launch_bounds__(256) void convqk(const float* __restrict__ q,
                                              const float* __restrict__ k,
                                              unsigned short* __restrict__ qo,
                                              unsigned short* __restrict__ ko) {
  const int NT = NELEM / 4;  // float4 chunks per tensor
  for (int i = blockIdx.x * 256 + threadIdx.x; i < 2 * NT; i += gridDim.x * 256) {
    const float4* src; unsigned short* dst; int j = i;
    if (i < NT) { src = (const float4*)q; dst = qo; }
    else        { src = (const float4*)k; dst = ko; j -= NT; }
    float4 v = src[j];
    ushort4 o;
    o.x = f2h(v.x); o.y = f2h(v.y); o.z = f2h(v.z); o.w = f2h(v.w);
    *(ushort4*)(dst + (size_t)j * 4) = o;
  }
}

// ---------------- pre-kernel 2: V [bh][s][d] fp32 -> Vt [bh][d][s] fp16 ----
__global__ __launch_bounds__(256) void transv(const float* __restrict__ v,
                                              unsigned short* __restrict__ vt) {
  __shared__ unsigned short lv[64 * 128];  // [s_local][d], 16KB
  const int tid = threadIdx.x;
  const int bh = blockIdx.y;
  const int s0 = blockIdx.x * 64;
  const float* vsrc = v + ((size_t)bh * SQ + s0) * DH;
  // stage + convert (coalesced float4 reads)
  for (int it = 0; it < 8; ++it) {
    int fi = it * 256 + tid;        // float4 index, 32 per row
    int sL = fi >> 5;
    int dL = (fi & 31) * 4;
    float4 val = *(const float4*)(vsrc + (size_t)sL * DH + dL);
    lv[sL * 128 + dL + 0] = f2h(val.x);
    lv[sL * 128 + dL + 1] = f2h(val.y);
    lv[sL * 128 + dL + 2] = f2h(val.z);
    lv[sL * 128 + dL + 3] = f2h(val.w);
  }
  __syncthreads();
  // transposed write-out: each thread emits 8 keys of one d-row (16B)
  for (int it = 0; it < 4; ++it) {
    int ci = it * 256 + tid;        // 1024 chunks: d = ci&127, sgroup = ci>>7
    int dL = ci & 127;
    int sg = ci >> 7;
    u16x8 o;
    #pragma unroll
    for (int j = 0; j < 8; ++j) o[j] = lv[(sg * 8 + j) * 128 + dL];
    *(u16x8*)(vt + ((size_t)bh * DH + dL) * SQ + s0 + sg * 8) = o;
  }
}

// ---------------- main flash-attention kernel ----------------
__global__ __launch_bounds__(256) void fattn(const unsigned short* __restrict__ Qb,
                                             const unsigned short* __restrict__ Kb,
                                             const unsigned short* __restrict__ Vt,
                                             float* __restrict__ Out) {
  __shared__ char smem[49152];   // [0,16K) K-tile, [16K,32K) Vt-tile, [32K,48K) P (4K/wave)
                                 // Q staging aliases [0,32K)
  const int tid  = threadIdx.x;
  const int wave = tid >> 6;
  const int lane = tid & 63;
  const int quad = lane >> 4;
  const int c    = lane & 15;
  const int bh   = blockIdx.y;
  const int qb   = 15 - (int)blockIdx.x;           // big blocks dispatched first
  const int mt0i = wave, mt1i = 7 - wave;          // causal-balanced m-tile pair
  const int rowg0 = qb * BM + mt0i * 16;
  const int rowg1 = qb * BM + mt1i * 16;

  char* sK = smem;
  char* sV = smem + 16384;
  char* sP = smem + 32768 + wave * 4096;

  // ---- stage Q tile (128 rows x 128 d, fp16, swizzled), read frags ----
  const unsigned short* Qbase = Qb + ((size_t)bh * SQ + qb * BM) * DH;
  #pragma unroll
  for (int it = 0; it < 8; ++it) {
    int gi  = it * 256 + tid;          // group index 0..2047 (16 groups/row)
    int row = gi >> 4;
    int dg  = (gi & 15) ^ (row & 7);   // swizzle: LDS group holds this d-group
    gload16(smem + (it * 256 + wave * 64) * 16, Qbase + (size_t)row * DH + dg * 8);
  }
  __syncthreads();
  f16x8 qf[2][4];
  #pragma unroll
  for (int mt = 0; mt < 2; ++mt) {
    int lr = (mt ? mt1i : mt0i) * 16 + c;
    #pragma unroll
    for (int ch = 0; ch < 4; ++ch) {
      int sg = (ch * 4 + quad) ^ (lr & 7);
      qf[mt][ch] = *(const f16x8*)(smem + lr * 256 + sg * 16);
    }
  }
  __syncthreads();

  f32x4 acc[2][8];
  #pragma unroll
  for (int mt = 0; mt < 2; ++mt)
    #pragma unroll
    for (int dt = 0; dt < 8; ++dt) acc[mt][dt] = (f32x4){0.f, 0.f, 0.f, 0.f};
  float mrow[2][4], lrow[2][4];
  #pragma unroll
  for (int mt = 0; mt < 2; ++mt)
    #pragma unroll
    for (int r = 0; r < 4; ++r) { mrow[mt][r] = -1e30f; lrow[mt][r] = 0.f; }

  const unsigned short* Kbase = Kb + (size_t)bh * SQ * DH;
  const unsigned short* Vbase = Vt + (size_t)bh * DH * SQ;
  const int nkt = 2 * qb + 2;

  for (int kt = 0; kt < nkt; ++kt) {
    const int k0 = kt * BN;
    // ---- stage K tile (64 keys x 128 d) and Vt tile (128 d x 64 keys) ----
    #pragma unroll
    for (int it = 0; it < 4; ++it) {
      int gi  = it * 256 + tid;
      int key = gi >> 4;
      int dg  = (gi & 15) ^ (key & 7);
      gload16(sK + (it * 256 + wave * 64) * 16,
              Kbase + (size_t)(k0 + key) * DH + dg * 8);
    }
    #pragma unroll
    for (int it = 0; it < 4; ++it) {
      int gi = it * 256 + tid;
      int d  = gi >> 3;
      int kg = (gi & 7) ^ (d & 7);
      gload16(sV + (it * 256 + wave * 64) * 16,
              Vbase + (size_t)d * SQ + k0 + kg * 8);
    }
    __syncthreads();

    const bool act0 = (k0 <= rowg0 + 15);   // act for mt1 is always true (wave-uniform)

    // ---- S = Q K^T (16x16x32 mfma), C-layout: col=lane&15, row=quad*4+r ----
    f32x4 sc[2][4];
    #pragma unroll
    for (int mt = 0; mt < 2; ++mt)
      #pragma unroll
      for (int nt = 0; nt < 4; ++nt) sc[mt][nt] = (f32x4){0.f, 0.f, 0.f, 0.f};
    #pragma unroll
    for (int nt = 0; nt < 4; ++nt) {
      int keyl = nt * 16 + c;
      #pragma unroll
      for (int ch = 0; ch < 4; ++ch) {
        int sg = (ch * 4 + quad) ^ (keyl & 7);
        f16x8 kf = *(const f16x8*)(sK + keyl * 256 + sg * 16);
        sc[0][nt] = __builtin_amdgcn_mfma_f32_16x16x32_f16(qf[0][ch], kf, sc[0][nt], 0, 0, 0);
        sc[1][nt] = __builtin_amdgcn_mfma_f32_16x16x32_f16(qf[1][ch], kf, sc[1][nt], 0, 0, 0);
      }
    }

    // ---- online softmax + P write (fp16, swizzled per-wave region) ----
    // NOTE: compile-time-unrolled mt loop with guard INSIDE. A runtime lower
    // bound here demotes sc/acc/mrow/lrow to scratch (R2: 1.78 GB writes).
    #pragma unroll
    for (int mt = 0; mt < 2; ++mt) {
      if (mt == 0 && !act0) continue;       // wave-uniform skip
      const int rowgm = mt ? rowg1 : rowg0;
      if (k0 + 63 > rowgm) {   // causal mask needed on this tile
        #pragma unroll
        for (int nt = 0; nt < 4; ++nt) {
          int key = k0 + nt * 16 + c;
          #pragma unroll
          for (int r = 0; r < 4; ++r) {
            int row = rowgm + quad * 4 + r;
            if (key > row) sc[mt][nt][r] = -1e30f;
          }
        }
      }
      #pragma unroll
      for (int r = 0; r < 4; ++r) {
        float cm = fmaxf(fmaxf(sc[mt][0][r], sc[mt][1][r]),
                         fmaxf(sc[mt][2][r], sc[mt][3][r]));
        cm = redmax16(cm);
        float mo = mrow[mt][r];
        float mn = fmaxf(mo, cm);
        float al = __expf(mo - mn);
        float rs = 0.f;
        int lrp = mt * 16 + quad * 4 + r;
        #pragma unroll
        for (int nt = 0; nt < 4; ++nt) {
          float p = __expf(sc[mt][nt][r] - mn);
          rs += p;
          int colg = nt * 16 + c;
          int sg = (colg >> 3) ^ (lrp & 7);
          *(unsigned short*)(sP + lrp * 128 + sg * 16 + (colg & 7) * 2) = f2h(p);
        }
        rs = redsum16(rs);
        lrow[mt][r] = lrow[mt][r] * al + rs;
        mrow[mt][r] = mn;
        #pragma unroll
        for (int dt = 0; dt < 8; ++dt) acc[mt][dt][r] *= al;
      }
    }

    // ---- O += P V  (P: A-layout from LDS, Vt: B-layout) ----
    #pragma unroll
    for (int ch = 0; ch < 2; ++ch) {
      f16x8 pf0, pf1;
      if (act0) {
        int lrp = c;                      // mt0 rows 0..15 of wave region
        int sg = (ch * 4 + quad) ^ (lrp & 7);
        pf0 = *(const f16x8*)(sP + lrp * 128 + sg * 16);
      }
      {
        int lrp = 16 + c;
        int sg = (ch * 4 + quad) ^ (lrp & 7);
        pf1 = *(const f16x8*)(sP + lrp * 128 + sg * 16);
      }
      #pragma unroll
      for (int dt = 0; dt < 8; ++dt) {
        int d = dt * 16 + c;
        int sg = (ch * 4 + quad) ^ (d & 7);
        f16x8 vf = *(const f16x8*)(sV + d * 128 + sg * 16);
        if (act0)
          acc[0][dt] = __builtin_amdgcn_mfma_f32_16x16x32_f16(pf0, vf, acc[0][dt], 0, 0, 0);
        acc[1][dt] = __builtin_amdgcn_mfma_f32_16x16x32_f16(pf1, vf, acc[1][dt], 0, 0, 0);
      }
    }
    __syncthreads();   // protect sK/sV/sP before next stage
  }

  // ---- epilogue: O / l ----
  #pragma unroll
  for (int mt = 0; mt < 2; ++mt) {
    const int rowgm = mt ? rowg1 : rowg0;
    #pragma unroll
    for (int r = 0; r < 4; ++r) {
      float inv = 1.0f / lrow[mt][r];
      int row = rowgm + quad * 4 + r;
      float* op = Out + ((size_t)bh * SQ + row) * DH + c;
      #pragma unroll
      for (int dt = 0; dt < 8; ++dt) op[dt * 16] = acc[mt][dt][r] * inv;
    }
  }
}

extern "C" void kernel_launch(void* const* d_in, const int* in_sizes, int n_in,
                              void* d_out, int out_size, void* d_ws, size_t ws_size,
                              hipStream_t stream) {
  const float* q = (const float*)d_in[0];
  const float* k = (const float*)d_in[1];
  const float* v = (const float*)d_in[2];
  // d_in[3] (mask) is guaranteed tril-causal; handled analytically.
  float* out = (float*)d_out;

  unsigned short* qws = (unsigned short*)d_ws;           // 16 MiB
  unsigned short* kws = qws + NELEM;                     // 16 MiB
  unsigned short* vws = kws + NELEM;                     // 16 MiB (transposed)

  convqk<<<4096, 256, 0, stream>>>(q, k, qws, kws);
  transv<<<dim3(SQ / 64, 32), 256, 0, stream>>>(v, vws);
  fattn<<<dim3(16, 32), 256, 0, stream>>>(qws, kws, vws, out);
}

// Round 4
// 216.915 us; speedup vs baseline: 6.0058x; 1.7572x over previous
//
#include <hip/hip_runtime.h>

// FlashAttention fwd, causal, no scale. B=2,H=16,S=2048,D=128, fp32 in/out.
// R4 design: S^T orientation (mfma(kf,qf)) so each lane owns a full query row
// -> softmax = in-register reduce + 2 shuffles, P-write = 4x ds_write_b64.
// BM=64 (4 waves x 16 rows), BN=64, LDS 40KB -> 4 WG/CU = 16 waves/CU.
// Q converted fp32->fp16 inside fattn; pre-kernel converts K and V^T only.
// History: R1 bf16 absmax 0.155 (fail) -> fp16 0.031; R2 runtime-bound mt loop
// caused scratch demotion (1.78GB writes); R3 fixed, 244us but latency-bound
// (22% busy, ~98 DS ops/wave/kt in softmax chains).

#define SQ 2048
#define DH 128
#define BM 64
#define BN 64
#define NELEM 8388608   // B*H*S*D

typedef _Float16 f16x8 __attribute__((ext_vector_type(8)));
typedef float f32x4 __attribute__((ext_vector_type(4)));
typedef unsigned short u16x8 __attribute__((ext_vector_type(8)));

typedef __attribute__((address_space(3))) void lds_t;
typedef __attribute__((address_space(1))) void gmem_t;

__device__ __forceinline__ void gload16(void* lds, const void* g) {
  __builtin_amdgcn_global_load_lds((const gmem_t*)g, (lds_t*)lds, 16, 0, 0);
}

__device__ __forceinline__ unsigned short f2h(float f) {
  return __builtin_bit_cast(unsigned short, (_Float16)f);   // v_cvt_f16_f32 RNE
}

// ---------------- pre-kernel: K fp32->fp16 flat; V fp32 -> Vt[bh][d][s] fp16
__global__ __launch_bounds__(256) void prep(const float* __restrict__ k,
                                            const float* __restrict__ v,
                                            unsigned short* __restrict__ ko,
                                            unsigned short* __restrict__ vt) {
  const int tid = threadIdx.x;
  const int bx = blockIdx.x;
  if (bx < 1024) {
    // V transpose tile: 64 s x 128 d
    __shared__ unsigned short lv[64 * 132];   // pad 128->132 to break bank stride
    const int bh = bx >> 5;
    const int s0 = (bx & 31) * 64;
    const float* vs = v + ((size_t)bh * SQ + s0) * DH;
    #pragma unroll
    for (int it = 0; it < 8; ++it) {
      int fi = it * 256 + tid;
      int sL = fi >> 5;
      int dL = (fi & 31) * 4;
      float4 val = *(const float4*)(vs + (size_t)sL * DH + dL);
      ushort4 o;
      o.x = f2h(val.x); o.y = f2h(val.y); o.z = f2h(val.z); o.w = f2h(val.w);
      *(ushort4*)(lv + sL * 132 + dL) = o;
    }
    __syncthreads();
    // store: consecutive lanes cover consecutive s (128B segments per d-row)
    #pragma unroll
    for (int it = 0; it < 4; ++it) {
      int ci = it * 256 + tid;     // 1024 chunks: dL = ci>>3, sg = ci&7
      int dL = ci >> 3;
      int sg = ci & 7;
      u16x8 o;
      #pragma unroll
      for (int j = 0; j < 8; ++j) o[j] = lv[(sg * 8 + j) * 132 + dL];
      *(u16x8*)(vt + ((size_t)bh * DH + dL) * SQ + s0 + sg * 8) = o;
    }
  } else {
    // K conversion: 2048 blocks grid-stride over NELEM/4 float4 chunks
    const int NT = NELEM / 4;
    for (int i = (bx - 1024) * 256 + tid; i < NT; i += 2048 * 256) {
      float4 val = ((const float4*)k)[i];
      ushort4 o;
      o.x = f2h(val.x); o.y = f2h(val.y); o.z = f2h(val.z); o.w = f2h(val.w);
      ((ushort4*)ko)[i] = o;
    }
  }
}

// ---------------- main flash-attention kernel ----------------
// Grid 1024 flat. XCD-aware mapping: xcd = t&7 owns bh in [xcd*4, xcd*4+4);
// per-XCD rounds pair qb with 31-qb so each CU's 4 WGs sum to ~66 kt-units.
__global__ __launch_bounds__(256, 4) void fattn(const float* __restrict__ Qf,
                                                const unsigned short* __restrict__ Kh,
                                                const unsigned short* __restrict__ Vth,
                                                float* __restrict__ Out) {
  __shared__ char smem[40960];  // [0,16K) sK (Q staging aliases), [16K,32K) sV,
                                // [32K,40K) sP: 2KB/wave (16 rows x 128B)
  const int tid  = threadIdx.x;
  const int wave = tid >> 6;
  const int lane = tid & 63;
  const int quad = lane >> 4;
  const int c    = lane & 15;

  // block swizzle: balance + L2 locality
  const int t     = (int)blockIdx.x;
  const int xcd   = t & 7;
  const int idx   = t >> 3;
  const int cu    = idx & 31;
  const int round = idx >> 5;               // 0..3
  const int bh    = xcd * 4 + round;
  int qb;
  {
    int b0 = (cu + 8 * (round >> 1)) & 31;
    qb = (round & 1) ? (31 - b0) : b0;      // rounds: q, 31-q, q+8, 31-(q+8)
  }
  const int rowbase = qb * BM;

  char* sK = smem;
  char* sV = smem + 16384;
  char* sP = smem + 32768 + wave * 2048;

  // ---- stage Q (fp32 -> fp16) into sK region, swizzled; read B-frags ----
  const float* Qg = Qf + ((size_t)bh * SQ + rowbase) * DH;
  #pragma unroll
  for (int it = 0; it < 8; ++it) {
    int gi  = it * 256 + tid;      // 2048 units of 4 floats
    int row = gi >> 5;             // 0..63
    int sub = gi & 31;             // 4-float unit within row
    float4 qv = *(const float4*)(Qg + (size_t)row * DH + sub * 4);
    ushort4 h;
    h.x = f2h(qv.x); h.y = f2h(qv.y); h.z = f2h(qv.z); h.w = f2h(qv.w);
    int gr = (sub >> 1) ^ (row & 7);        // 16B-group swizzle
    *(ushort4*)(smem + row * 256 + gr * 16 + (sub & 1) * 8) = h;
  }
  __syncthreads();
  f16x8 qf[4];
  {
    int rl = wave * 16 + c;                 // wave's row (tile-local)
    #pragma unroll
    for (int ch = 0; ch < 4; ++ch) {
      int gr = (ch * 4 + quad) ^ (c & 7);   // rl&7 == c&7
      qf[ch] = *(const f16x8*)(smem + rl * 256 + gr * 16);
    }
  }
  __syncthreads();

  f32x4 acc[8];                             // O^T: d = dt*16+quad*4+r, row = c
  #pragma unroll
  for (int dt = 0; dt < 8; ++dt) acc[dt] = (f32x4){0.f, 0.f, 0.f, 0.f};
  float mo = -1e30f, lrow = 0.f;            // per-lane row stats (row = c)

  const unsigned short* Kbase = Kh + (size_t)bh * SQ * DH;
  const unsigned short* Vbase = Vth + (size_t)bh * DH * SQ;
  const int nkt = qb + 1;

  for (int kt = 0; kt < nkt; ++kt) {
    const int k0 = kt * BN;
    // ---- stage K (64 keys x 128 d) and Vt (128 d x 64 keys) ----
    #pragma unroll
    for (int it = 0; it < 4; ++it) {
      int gi  = it * 256 + tid;
      int key = gi >> 4;
      int dg  = (gi & 15) ^ (key & 7);
      gload16(sK + (it * 256 + wave * 64) * 16,
              Kbase + (size_t)(k0 + key) * DH + dg * 8);
    }
    #pragma unroll
    for (int it = 0; it < 4; ++it) {
      int gi = it * 256 + tid;
      int d  = gi >> 3;
      int kg = (gi & 7) ^ (d & 7);
      gload16(sV + (it * 256 + wave * 64) * 16,
              Vbase + (size_t)d * SQ + k0 + kg * 8);
    }
    __syncthreads();

    const bool diag  = (kt == qb);
    const int ntmax  = diag ? wave : 3;         // wave-uniform: skip key-tiles
    const int chmax  = diag ? (wave >> 1) : 1;  // fully above the diagonal

    // ---- S^T = K Q^T: D[m=key][n=row]; col=c=row, key = nt*16+quad*4+r ----
    f32x4 sc[4];
    #pragma unroll
    for (int nt = 0; nt < 4; ++nt) sc[nt] = (f32x4){0.f, 0.f, 0.f, 0.f};
    #pragma unroll
    for (int nt = 0; nt < 4; ++nt) {
      if (nt <= ntmax) {
        int keyl = nt * 16 + c;
        #pragma unroll
        for (int ch = 0; ch < 4; ++ch) {
          int gr = (ch * 4 + quad) ^ (c & 7);   // keyl&7 == c&7
          f16x8 kf = *(const f16x8*)(sK + keyl * 256 + gr * 16);
          sc[nt] = __builtin_amdgcn_mfma_f32_16x16x32_f16(kf, qf[ch], sc[nt], 0, 0, 0);
        }
      }
    }

    // ---- causal mask on diagonal tile (also covers skipped nt tiles) ----
    if (diag) {
      int rl = wave * 16 + c;
      #pragma unroll
      for (int nt = 0; nt < 4; ++nt)
        #pragma unroll
        for (int r = 0; r < 4; ++r)
          if (nt * 16 + quad * 4 + r > rl) sc[nt][r] = -1e30f;
    }

    // ---- online softmax: lane owns row c; 16 vals in-reg + 2 shuffles ----
    float cm = -1e30f;
    #pragma unroll
    for (int nt = 0; nt < 4; ++nt)
      #pragma unroll
      for (int r = 0; r < 4; ++r) cm = fmaxf(cm, sc[nt][r]);
    cm = fmaxf(cm, __shfl_xor(cm, 16));
    cm = fmaxf(cm, __shfl_xor(cm, 32));
    float mn = fmaxf(mo, cm);
    float al = __expf(mo - mn);
    float rs = 0.f;
    ushort4 pk[4];
    #pragma unroll
    for (int nt = 0; nt < 4; ++nt) {
      #pragma unroll
      for (int r = 0; r < 4; ++r) {
        float p = __expf(sc[nt][r] - mn);
        rs += p;
        ((unsigned short*)&pk[nt])[r] = f2h(p);
      }
    }
    rs += __shfl_xor(rs, 16);
    rs += __shfl_xor(rs, 32);
    lrow = lrow * al + rs;
    mo = mn;
    #pragma unroll
    for (int dt = 0; dt < 8; ++dt) acc[dt] *= al;

    // ---- P write: row-major [row c][64 keys], 8-key-group swizzle ^(c&7) ----
    #pragma unroll
    for (int nt = 0; nt < 4; ++nt) {
      int g8 = nt * 2 + (quad >> 1);
      *(ushort4*)(sP + c * 128 + ((g8 ^ (c & 7)) * 16) + (quad & 1) * 8) = pk[nt];
    }

    // ---- O^T += Vt * P: A = Vt frags, B = P frags ----
    #pragma unroll
    for (int ch = 0; ch < 2; ++ch) {
      if (ch <= chmax) {
        f16x8 pf = *(const f16x8*)(sP + c * 128 + (((ch * 4 + quad) ^ (c & 7)) * 16));
        #pragma unroll
        for (int dt = 0; dt < 8; ++dt) {
          int d  = dt * 16 + c;
          int gr = (ch * 4 + quad) ^ (c & 7);   // d&7 == c&7
          f16x8 vf = *(const f16x8*)(sV + d * 128 + gr * 16);
          acc[dt] = __builtin_amdgcn_mfma_f32_16x16x32_f16(vf, pf, acc[dt], 0, 0, 0);
        }
      }
    }
    __syncthreads();   // protect sK/sV before next staging
  }

  // ---- epilogue: O[row][d] = acc / l; float4 per dt ----
  const float inv = 1.0f / lrow;
  const int rowg = rowbase + wave * 16 + c;
  float* op = Out + ((size_t)bh * SQ + rowg) * DH;
  #pragma unroll
  for (int dt = 0; dt < 8; ++dt) {
    float4 o;
    o.x = acc[dt][0] * inv;
    o.y = acc[dt][1] * inv;
    o.z = acc[dt][2] * inv;
    o.w = acc[dt][3] * inv;
    *(float4*)(op + dt * 16 + quad * 4) = o;
  }
}

extern "C" void kernel_launch(void* const* d_in, const int* in_sizes, int n_in,
                              void* d_out, int out_size, void* d_ws, size_t ws_size,
                              hipStream_t stream) {
  const float* q = (const float*)d_in[0];
  const float* k = (const float*)d_in[1];
  const float* v = (const float*)d_in[2];
  // d_in[3] (mask) is guaranteed tril-causal; handled analytically.
  float* out = (float*)d_out;

  unsigned short* kws = (unsigned short*)d_ws;           // 16 MiB
  unsigned short* vws = kws + NELEM;                     // 16 MiB (transposed)

  prep<<<3072, 256, 0, stream>>>(k, v, kws, vws);
  fattn<<<1024, 256, 0, stream>>>(q, kws, vws, out);
}